// Round 12
// baseline (27.583 us; speedup 1.0000x reference)
//
#include <hip/hip_runtime.h>
#include <math.h>

constexpr float INV_B = 1.0f / 16384.0f;
constexpr float BN_EPS_C = 1e-5f;
constexpr int NUM_USERS_C = 1000000;

typedef __attribute__((ext_vector_type(8))) short bf16x8;
typedef __attribute__((ext_vector_type(4))) float f32x4;

__device__ inline unsigned short f2bf(float f) {
    union { float f; unsigned u; } v; v.f = f;
    unsigned r = v.u + 0x7FFFu + ((v.u >> 16) & 1u);   // RNE
    return (unsigned short)(r >> 16);
}
__device__ inline float bf2f(unsigned short h) {
    union { unsigned u; float f; } v; v.u = ((unsigned)h) << 16; return v.f;
}
__device__ inline bf16x8 pack8(float4 a, float4 b) {
    bf16x8 sv;
    sv[0] = (short)f2bf(a.x); sv[1] = (short)f2bf(a.y);
    sv[2] = (short)f2bf(a.z); sv[3] = (short)f2bf(a.w);
    sv[4] = (short)f2bf(b.x); sv[5] = (short)f2bf(b.y);
    sv[6] = (short)f2bf(b.z); sv[7] = (short)f2bf(b.w);
    return sv;
}
// XOR swizzles for pitch-256B / pitch-512B row-major bf16 tiles
__device__ inline unsigned swz256(int r, int kb) { return (unsigned)(r * 256 + (kb ^ ((r & 7) << 4))); }
__device__ inline unsigned swz512(int r, int kb) { return (unsigned)(r * 512 + (kb ^ ((r & 7) << 4))); }

// ---------------------------------------------------------------------------
// K0: one-time weight conversion f32 -> bf16 fragment-image layout, plus
//     zeroing of the stat replica buffers (8 replicas each = 6144 f32).
// ---------------------------------------------------------------------------
__global__ __launch_bounds__(256) void wd_k0(
    const float* __restrict__ W1, const float* __restrict__ W2,
    unsigned short* __restrict__ img1, unsigned short* __restrict__ img2,
    float* __restrict__ stats)
{
    int t = blockIdx.x * 256 + threadIdx.x;        // grid 48*256 = 12288
    if (t < 6144) stats[t] = 0.f;                  // part1 (4096) + part2 (2048)
    if (t < 4096) {
        int a = t * 16, n = a >> 8, ks = a & 255;
        int k0 = (ks ^ ((n & 7) << 4)) >> 1;
        const float* src = W1 + (size_t)n * 128 + k0;
        float4 va = ((const float4*)src)[0];
        float4 vb = ((const float4*)src)[1];
        *(bf16x8*)((char*)img1 + a) = pack8(va, vb);
    } else if (t < 8192) {
        int tt = t - 4096;
        int a = tt * 16, h = a >> 15, rem = a & 32767, n = rem >> 8, ks = rem & 255;
        int kb = ks ^ ((n & 7) << 4);
        int k0 = h * 128 + (kb >> 1);
        const float* src = W2 + (size_t)n * 256 + k0;
        float4 va = ((const float4*)src)[0];
        float4 vb = ((const float4*)src)[1];
        *(bf16x8*)((char*)img2 + a) = pack8(va, vb);
    }
}

// ---------------------------------------------------------------------------
// K1: 256 blocks x 64 rows. X-gather + wide-gather issued first; B-fragments
//     (img1, L2-hot) reused across 64 rows (2x the arithmetic intensity of
//     the 32-row version). GEMM, +b1, ReLU -> h1s image (64r x 512B tiles);
//     wide -> wideB; stats -> part1[8 reps].
// ---------------------------------------------------------------------------
__global__ __launch_bounds__(512, 2) void wd_k1(
    const int* __restrict__ ui, const int* __restrict__ ii,
    const float* __restrict__ utab, const float* __restrict__ itab,
    const float* __restrict__ wide_w,
    const unsigned short* __restrict__ img1, const float* __restrict__ b1,
    unsigned short* __restrict__ h1s, float* __restrict__ wideB,
    float* __restrict__ part1)
{
    __shared__ char Xs[16384];       // 64 x 256B, swizzled
    __shared__ char Bnc[32768];      // bounce: 64 x 512B, swizzled
    __shared__ float sstat[512];

    const int tid = threadIdx.x, bid = blockIdx.x, row0 = bid * 64;
    const int w = tid >> 6, lane = tid & 63, lr = lane & 15, lk = lane >> 4;

    // issue X-gather loads first (random HBM, longest latency): 2 chunks/thread
    float4 gva[2], gvb[2];
    int grow_[2], gkc_[2];
#pragma unroll
    for (int it = 0; it < 2; ++it) {
        int idx = it * 512 + tid;
        int row = idx >> 4, kc = idx & 15;
        grow_[it] = row; gkc_[it] = kc;
        const float* src = (kc < 8)
            ? utab + (size_t)ui[row0 + row] * 64 + kc * 8
            : itab + (size_t)ii[row0 + row] * 64 + (kc - 8) * 8;
        gva[it] = ((const float4*)src)[0];
        gvb[it] = ((const float4*)src)[1];
    }

    // wide-path gather rides the same latency window (tid<64)
    float wide_r = 0.f;
    if (tid < 64)
        wide_r = wide_w[ui[row0 + tid]] + wide_w[NUM_USERS_C + ii[row0 + tid]];

    // preload B fragments for this wave's 32 columns (bf16 image, L2-hot) + bias
    bf16x8 bfr[2][4];
    float bias_r[2];
#pragma unroll
    for (int nj = 0; nj < 2; ++nj) {
        int n = w * 32 + nj * 16 + lr;
        bias_r[nj] = b1[n];
        const char* bp = (const char*)img1 + n * 256;
        int sx = (n & 7) << 4;
#pragma unroll
        for (int kst = 0; kst < 4; ++kst)
            bfr[nj][kst] = *(const bf16x8*)(bp + ((kst * 64 + lk * 16) ^ sx));
    }

    // write gathered X to LDS
#pragma unroll
    for (int it = 0; it < 2; ++it)
        *(bf16x8*)(Xs + swz256(grow_[it], gkc_[it] * 16)) = pack8(gva[it], gvb[it]);
    __syncthreads();

    f32x4 acc[4][2];
#pragma unroll
    for (int mi = 0; mi < 4; ++mi)
#pragma unroll
        for (int nj = 0; nj < 2; ++nj) acc[mi][nj] = (f32x4){0.f, 0.f, 0.f, 0.f};

#pragma unroll
    for (int kst = 0; kst < 4; ++kst) {
        int kb = kst * 64 + lk * 16;
#pragma unroll
        for (int mi = 0; mi < 4; ++mi) {
            bf16x8 a = *(const bf16x8*)(Xs + swz256(mi * 16 + lr, kb));
#pragma unroll
            for (int nj = 0; nj < 2; ++nj)
                acc[mi][nj] = __builtin_amdgcn_mfma_f32_16x16x32_bf16(a, bfr[nj][kst], acc[mi][nj], 0, 0, 0);
        }
    }

    // epilogue: bias + relu + bf16, bounce to Bnc, per-col stats over 64 rows
#pragma unroll
    for (int nj = 0; nj < 2; ++nj) {
        int col = w * 32 + nj * 16 + lr;
        float s = 0.f, q = 0.f;
#pragma unroll
        for (int mi = 0; mi < 4; ++mi)
#pragma unroll
            for (int reg = 0; reg < 4; ++reg) {
                int rl = mi * 16 + lk * 4 + reg;
                float v = fmaxf(acc[mi][nj][reg] + bias_r[nj], 0.f);
                unsigned short hb = f2bf(v);
                float vr = bf2f(hb);
                s += vr; q += vr * vr;
                *(unsigned short*)(Bnc + swz512(rl, col * 2)) = hb;
            }
        s += __shfl_xor(s, 16); s += __shfl_xor(s, 32);
        q += __shfl_xor(q, 16); q += __shfl_xor(q, 32);
        if (lk == 0) { sstat[col] = s; sstat[256 + col] = q; }   // unique writer per col
    }
    __syncthreads();

    // dump 32 KB tile (64B per thread, coalesced) + wide store + stats replica add
#pragma unroll
    for (int it = 0; it < 4; ++it) {
        int a = it * 8192 + tid * 16;
        *(bf16x8*)((char*)h1s + (size_t)bid * 32768 + a) = *(const bf16x8*)(Bnc + a);
    }
    if (tid < 64) wideB[row0 + tid] = wide_r;
    atomicAdd(&part1[(size_t)(bid & 7) * 512 + tid], sstat[tid]);
}

// ---------------------------------------------------------------------------
// K2: 256 blocks x 64 rows. T14 split: raw h1 tile loads issued to registers
//     FIRST, BN coeffs + B-preload + bias computed under that latency, then
//     transform + ds_write after the barrier. B-fragments reused across 64
//     rows. GEMM -> +b2, ReLU -> h2s image (64r x 256B); stats -> part2.
// ---------------------------------------------------------------------------
__global__ __launch_bounds__(512, 2) void wd_k2(
    const unsigned short* __restrict__ h1s, const float* __restrict__ part1,
    const float* __restrict__ g1, const float* __restrict__ be1,
    const unsigned short* __restrict__ img2, const float* __restrict__ b2,
    unsigned short* __restrict__ h2s, float* __restrict__ part2)
{
    __shared__ char As[32768];       // 64 x 512B, swizzled (h1 image layout)
    __shared__ char Bnc[16384];      // bounce: 64 x 256B, swizzled
    __shared__ float a1s[256], c1s[256], sstat[256];

    const int tid = threadIdx.x, bid = blockIdx.x;
    const int w = tid >> 6, lane = tid & 63, lr = lane & 15, lk = lane >> 4;
    const int n = w * 16 + lr;            // this lane's output column (0..127)
    const int sx = (n & 7) << 4;

    // (1) issue raw A-tile loads to registers (4 x 16B per thread)
    bf16x8 hv[4];
#pragma unroll
    for (int it = 0; it < 4; ++it)
        hv[it] = *(const bf16x8*)((const char*)h1s + (size_t)bid * 32768 + it * 8192 + tid * 16);

    // (2) preload B fragments from img2 (L2-hot) + bias
    const float bias = b2[n];
    bf16x8 bfr[8];
#pragma unroll
    for (int h = 0; h < 2; ++h)
#pragma unroll
        for (int kst = 0; kst < 4; ++kst)
            bfr[h * 4 + kst] = *(const bf16x8*)((const char*)img2 + h * 32768 + n * 256 + ((kst * 64 + lk * 16) ^ sx));

    // (3) BN1 coefficients from 8 replicas
    if (tid < 256) {
        float s = 0.f, q = 0.f;
#pragma unroll
        for (int r = 0; r < 8; ++r) { s += part1[r * 512 + tid]; q += part1[r * 512 + 256 + tid]; }
        float mu = s * INV_B;
        float var = fmaf(q, INV_B, -mu * mu);
        float rs = rsqrtf(var + BN_EPS_C);
        float a = g1[tid] * rs;
        a1s[tid] = a;
        c1s[tid] = fmaf(-mu, a, be1[tid]);
    }
    __syncthreads();

    // (4) transform + write A tile (value transform, layout preserved)
#pragma unroll
    for (int it = 0; it < 4; ++it) {
        int a = it * 8192 + tid * 16;
        int r = a >> 9, ks = a & 511;
        int k0 = (ks ^ ((r & 7) << 4)) >> 1;
        bf16x8 sv;
#pragma unroll
        for (int j = 0; j < 8; ++j) {
            float f = bf2f((unsigned short)hv[it][j]);
            f = fmaf(a1s[k0 + j], f, c1s[k0 + j]);
            sv[j] = (short)f2bf(f);
        }
        *(bf16x8*)(As + a) = sv;
    }
    __syncthreads();

    f32x4 acc[4];
#pragma unroll
    for (int mi = 0; mi < 4; ++mi) acc[mi] = (f32x4){0.f, 0.f, 0.f, 0.f};
    const int sxa = (lr & 7) << 4;
#pragma unroll
    for (int k8 = 0; k8 < 8; ++k8) {
        int kb = (k8 * 64 + lk * 16) ^ sxa;   // (mi*16+lr)&7 == lr&7
#pragma unroll
        for (int mi = 0; mi < 4; ++mi) {
            bf16x8 a = *(const bf16x8*)(As + (mi * 16 + lr) * 512 + kb);
            acc[mi] = __builtin_amdgcn_mfma_f32_16x16x32_bf16(a, bfr[k8], acc[mi], 0, 0, 0);
        }
    }

    // epilogue
    {
        float s = 0.f, q = 0.f;
#pragma unroll
        for (int mi = 0; mi < 4; ++mi)
#pragma unroll
            for (int reg = 0; reg < 4; ++reg) {
                int rl = mi * 16 + lk * 4 + reg;
                float v = fmaxf(acc[mi][reg] + bias, 0.f);
                unsigned short hb = f2bf(v);
                float vr = bf2f(hb);
                s += vr; q += vr * vr;
                *(unsigned short*)(Bnc + swz256(rl, n * 2)) = hb;
            }
        s += __shfl_xor(s, 16); s += __shfl_xor(s, 32);
        q += __shfl_xor(q, 16); q += __shfl_xor(q, 32);
        if (lk == 0) { sstat[n] = s; sstat[128 + n] = q; }
    }
    __syncthreads();

    // dump 16 KB tile + stats replica add
#pragma unroll
    for (int it = 0; it < 2; ++it) {
        int a = it * 8192 + tid * 16;
        *(bf16x8*)((char*)h2s + (size_t)bid * 16384 + a) = *(const bf16x8*)(Bnc + a);
    }
    if (tid < 256) atomicAdd(&part2[(size_t)(bid & 7) * 256 + tid], sstat[tid]);
}

// ---------------------------------------------------------------------------
// K3: BN2 folded into W3; per-row dot on h2s image (swizzle-aware reads)
//     + precomputed wide + sigmoid. 512 blocks x 32 rows.
// ---------------------------------------------------------------------------
__global__ __launch_bounds__(128, 4) void wd_k3(
    const float* __restrict__ wideB, const float* __restrict__ wide_b,
    const unsigned short* __restrict__ h2s, const float* __restrict__ part2,
    const float* __restrict__ g2, const float* __restrict__ be2,
    const float* __restrict__ W3, const float* __restrict__ b3,
    float* __restrict__ out)
{
    __shared__ float af[128], cf[128];
    const int tid = threadIdx.x, bid = blockIdx.x;
    const int r = tid >> 2, kq = tid & 3;
    const int row = bid * 32 + r;

    float wide = 0.f;
    if (kq == 0) wide = wideB[row];

    {
        float s = 0.f, q = 0.f;
#pragma unroll
        for (int rr = 0; rr < 8; ++rr) { s += part2[rr * 256 + tid]; q += part2[rr * 256 + 128 + tid]; }
        float mu = s * INV_B;
        float var = fmaf(q, INV_B, -mu * mu);
        float rs = rsqrtf(var + BN_EPS_C);
        float a = g2[tid] * rs;
        float c = fmaf(-mu, a, be2[tid]);
        float w3 = W3[tid];
        af[tid] = a * w3;
        cf[tid] = c * w3;
    }
    __syncthreads();

    // h2s tiles are 64 rows x 256B
    const int tile = row >> 6, rin = row & 63;
    const char* tb = (const char*)h2s + (size_t)tile * 16384 + rin * 256;
    float acc = 0.f;
#pragma unroll
    for (int j = 0; j < 4; ++j) {
        int ks = (kq * 64 + j * 16) ^ ((rin & 7) << 4);
        bf16x8 hv = *(const bf16x8*)(tb + ks);
#pragma unroll
        for (int e = 0; e < 8; ++e) {
            float h = bf2f((unsigned short)hv[e]);
            int k = kq * 32 + j * 8 + e;
            acc += fmaf(h, af[k], cf[k]);
        }
    }
    acc += __shfl_xor(acc, 1);
    acc += __shfl_xor(acc, 2);
    if (kq == 0) {
        float logit = acc + b3[0] + wide_b[0] + wide;
        out[row] = 1.f / (1.f + expf(-logit));
    }
}

extern "C" void kernel_launch(void* const* d_in, const int* in_sizes, int n_in,
                              void* d_out, int out_size, void* d_ws, size_t ws_size,
                              hipStream_t stream)
{
    const int*   ui     = (const int*)d_in[0];
    const int*   ii     = (const int*)d_in[1];
    const float* wide_w = (const float*)d_in[2];
    const float* wide_b = (const float*)d_in[3];
    const float* utab   = (const float*)d_in[4];
    const float* itab   = (const float*)d_in[5];
    const float* W1     = (const float*)d_in[6];
    const float* b1     = (const float*)d_in[7];
    const float* g1     = (const float*)d_in[8];
    const float* be1    = (const float*)d_in[9];
    const float* W2     = (const float*)d_in[10];
    const float* b2     = (const float*)d_in[11];
    const float* g2     = (const float*)d_in[12];
    const float* be2    = (const float*)d_in[13];
    const float* W3     = (const float*)d_in[14];
    const float* b3     = (const float*)d_in[15];
    float* outp = (float*)d_out;

    char* base = (char*)d_ws;
    float* part1 = (float*)base;                                   // 8*512 f32 = 16 KB
    float* part2 = (float*)(base + 16384);                         // 8*256 f32 = 8 KB
    unsigned short* img1 = (unsigned short*)(base + 49152);        // 64 KB
    unsigned short* img2 = (unsigned short*)(base + 49152 + 65536);
    float* wideB = (float*)(base + 49152 + 131072);                // 64 KB
    unsigned short* h1s  = (unsigned short*)(base + 49152 + 131072 + 65536);      // 8 MB
    unsigned short* h2s  = (unsigned short*)(base + 49152 + 131072 + 65536 + (size_t)256 * 32768);

    wd_k0<<<48, 256, 0, stream>>>(W1, W2, img1, img2, part1);
    wd_k1<<<256, 512, 0, stream>>>(ui, ii, utab, itab, wide_w, img1, b1, h1s, wideB, part1);
    wd_k2<<<256, 512, 0, stream>>>(h1s, part1, g1, be1, img2, b2, h2s, part2);
    wd_k3<<<512, 128, 0, stream>>>(wideB, wide_b, h2s, part2, g2, be2, W3, b3, outp);
}

// Round 13
// 25.708 us; speedup vs baseline: 1.0729x; 1.0729x over previous
//
#include <hip/hip_runtime.h>
#include <math.h>

constexpr float INV_B = 1.0f / 16384.0f;
constexpr float BN_EPS_C = 1e-5f;
constexpr int NUM_USERS_C = 1000000;

typedef __attribute__((ext_vector_type(8))) short bf16x8;
typedef __attribute__((ext_vector_type(4))) float f32x4;

__device__ inline unsigned short f2bf(float f) {
    union { float f; unsigned u; } v; v.f = f;
    unsigned r = v.u + 0x7FFFu + ((v.u >> 16) & 1u);   // RNE
    return (unsigned short)(r >> 16);
}
__device__ inline float bf2f(unsigned short h) {
    union { unsigned u; float f; } v; v.u = ((unsigned)h) << 16; return v.f;
}
__device__ inline bf16x8 pack8(float4 a, float4 b) {
    bf16x8 sv;
    sv[0] = (short)f2bf(a.x); sv[1] = (short)f2bf(a.y);
    sv[2] = (short)f2bf(a.z); sv[3] = (short)f2bf(a.w);
    sv[4] = (short)f2bf(b.x); sv[5] = (short)f2bf(b.y);
    sv[6] = (short)f2bf(b.z); sv[7] = (short)f2bf(b.w);
    return sv;
}
// XOR swizzles for pitch-256B / pitch-512B row-major bf16 tiles
__device__ inline unsigned swz256(int r, int kb) { return (unsigned)(r * 256 + (kb ^ ((r & 7) << 4))); }
__device__ inline unsigned swz512(int r, int kb) { return (unsigned)(r * 512 + (kb ^ ((r & 7) << 4))); }

// ---------------------------------------------------------------------------
// K0: one-time weight conversion f32 -> bf16 fragment-image layout, plus
//     zeroing of the stat replica buffers (8 replicas each = 6144 f32).
// ---------------------------------------------------------------------------
__global__ __launch_bounds__(256) void wd_k0(
    const float* __restrict__ W1, const float* __restrict__ W2,
    unsigned short* __restrict__ img1, unsigned short* __restrict__ img2,
    float* __restrict__ stats)
{
    int t = blockIdx.x * 256 + threadIdx.x;        // grid 48*256 = 12288
    if (t < 6144) stats[t] = 0.f;                  // part1 (4096) + part2 (2048)
    if (t < 4096) {
        int a = t * 16, n = a >> 8, ks = a & 255;
        int k0 = (ks ^ ((n & 7) << 4)) >> 1;
        const float* src = W1 + (size_t)n * 128 + k0;
        float4 va = ((const float4*)src)[0];
        float4 vb = ((const float4*)src)[1];
        *(bf16x8*)((char*)img1 + a) = pack8(va, vb);
    } else if (t < 8192) {
        int tt = t - 4096;
        int a = tt * 16, h = a >> 15, rem = a & 32767, n = rem >> 8, ks = rem & 255;
        int kb = ks ^ ((n & 7) << 4);
        int k0 = h * 128 + (kb >> 1);
        const float* src = W2 + (size_t)n * 256 + k0;
        float4 va = ((const float4*)src)[0];
        float4 vb = ((const float4*)src)[1];
        *(bf16x8*)((char*)img2 + a) = pack8(va, vb);
    }
}

// ---------------------------------------------------------------------------
// K1: 512 blocks x 32 rows. X-gather + wide-gather issued first (HBM random,
//     longest latency); B-fragments + bias preloaded under that latency.
//     GEMM, +b1, ReLU -> h1s image; wide -> wideB; stats -> part1[8 reps].
// ---------------------------------------------------------------------------
__global__ __launch_bounds__(512, 4) void wd_k1(
    const int* __restrict__ ui, const int* __restrict__ ii,
    const float* __restrict__ utab, const float* __restrict__ itab,
    const float* __restrict__ wide_w,
    const unsigned short* __restrict__ img1, const float* __restrict__ b1,
    unsigned short* __restrict__ h1s, float* __restrict__ wideB,
    float* __restrict__ part1)
{
    __shared__ char Xs[8192];        // 32 x 256B, swizzled
    __shared__ char Bnc[16384];      // bounce: 32 x 512B, swizzled
    __shared__ float sstat[512];

    const int tid = threadIdx.x, bid = blockIdx.x, row0 = bid * 32;
    const int w = tid >> 6, lane = tid & 63, lr = lane & 15, lk = lane >> 4;

    // issue X-gather loads first (random HBM ~900cy)
    const int grow = tid >> 4, gkc = tid & 15;
    const float* gsrc = (gkc < 8)
        ? utab + (size_t)ui[row0 + grow] * 64 + gkc * 8
        : itab + (size_t)ii[row0 + grow] * 64 + (gkc - 8) * 8;
    float4 gva = ((const float4*)gsrc)[0];
    float4 gvb = ((const float4*)gsrc)[1];

    // wide-path gather rides the same latency window (tid<32)
    float wide_r = 0.f;
    if (tid < 32)
        wide_r = wide_w[ui[row0 + tid]] + wide_w[NUM_USERS_C + ii[row0 + tid]];

    // preload B fragments for this wave's 32 columns (bf16 image, L2-hot)
    bf16x8 bfr[2][4];
    float bias_r[2];
#pragma unroll
    for (int nj = 0; nj < 2; ++nj) {
        int n = w * 32 + nj * 16 + lr;
        bias_r[nj] = b1[n];
        const char* bp = (const char*)img1 + n * 256;
        int sx = (n & 7) << 4;
#pragma unroll
        for (int kst = 0; kst < 4; ++kst)
            bfr[nj][kst] = *(const bf16x8*)(bp + ((kst * 64 + lk * 16) ^ sx));
    }

    // write gathered X to LDS
    *(bf16x8*)(Xs + swz256(grow, gkc * 16)) = pack8(gva, gvb);
    __syncthreads();

    f32x4 acc[2][2];
#pragma unroll
    for (int mi = 0; mi < 2; ++mi)
#pragma unroll
        for (int nj = 0; nj < 2; ++nj) acc[mi][nj] = (f32x4){0.f, 0.f, 0.f, 0.f};

#pragma unroll
    for (int kst = 0; kst < 4; ++kst) {
        int kb = kst * 64 + lk * 16;
        bf16x8 a0 = *(const bf16x8*)(Xs + swz256(lr, kb));
        bf16x8 a1v = *(const bf16x8*)(Xs + swz256(16 + lr, kb));
#pragma unroll
        for (int nj = 0; nj < 2; ++nj) {
            acc[0][nj] = __builtin_amdgcn_mfma_f32_16x16x32_bf16(a0, bfr[nj][kst], acc[0][nj], 0, 0, 0);
            acc[1][nj] = __builtin_amdgcn_mfma_f32_16x16x32_bf16(a1v, bfr[nj][kst], acc[1][nj], 0, 0, 0);
        }
    }

    // epilogue: bias + relu + bf16, bounce to Bnc, per-col stats
#pragma unroll
    for (int nj = 0; nj < 2; ++nj) {
        int col = w * 32 + nj * 16 + lr;
        float s = 0.f, q = 0.f;
#pragma unroll
        for (int mi = 0; mi < 2; ++mi)
#pragma unroll
            for (int reg = 0; reg < 4; ++reg) {
                int rl = mi * 16 + lk * 4 + reg;
                float v = fmaxf(acc[mi][nj][reg] + bias_r[nj], 0.f);
                unsigned short hb = f2bf(v);
                float vr = bf2f(hb);
                s += vr; q += vr * vr;
                *(unsigned short*)(Bnc + swz512(rl, col * 2)) = hb;
            }
        s += __shfl_xor(s, 16); s += __shfl_xor(s, 32);
        q += __shfl_xor(q, 16); q += __shfl_xor(q, 32);
        if (lk == 0) { sstat[col] = s; sstat[256 + col] = q; }   // unique writer per col
    }
    __syncthreads();

    // dump 16 KB tile (32B per thread, coalesced) + wide store + stats replica add
    {
        const char* s0 = Bnc + tid * 32;
        char* d0 = (char*)h1s + (size_t)bid * 16384 + tid * 32;
        *(bf16x8*)d0 = *(const bf16x8*)s0;
        *(bf16x8*)(d0 + 16) = *(const bf16x8*)(s0 + 16);
    }
    if (tid < 32) wideB[row0 + tid] = wide_r;
    atomicAdd(&part1[(size_t)(bid & 7) * 512 + tid], sstat[tid]);
}

// ---------------------------------------------------------------------------
// K2: 512 blocks x 32 rows. T14 split: raw h1 tile loads issued to registers
//     FIRST, BN coeffs + B-preload + bias computed under that latency, then
//     transform + ds_write after the barrier. GEMM -> +b2, ReLU -> h2s image;
//     stats -> part2[8 reps].
// ---------------------------------------------------------------------------
__global__ __launch_bounds__(512, 4) void wd_k2(
    const unsigned short* __restrict__ h1s, const float* __restrict__ part1,
    const float* __restrict__ g1, const float* __restrict__ be1,
    const unsigned short* __restrict__ img2, const float* __restrict__ b2,
    unsigned short* __restrict__ h2s, float* __restrict__ part2)
{
    __shared__ char As[16384];       // 32 x 512B, swizzled (h1 image layout)
    __shared__ char Bnc[8192];       // bounce: 32 x 256B, swizzled
    __shared__ float a1s[256], c1s[256], sstat[256];

    const int tid = threadIdx.x, bid = blockIdx.x;
    const int w = tid >> 6, lane = tid & 63, lr = lane & 15, lk = lane >> 4;
    const int n = w * 16 + lr;            // this lane's output column (0..127)
    const int sx = (n & 7) << 4;

    // (1) issue raw A-tile loads to registers (L2/L3 latency starts now)
    bf16x8 hv0 = *(const bf16x8*)((const char*)h1s + (size_t)bid * 16384 + tid * 16);
    bf16x8 hv1 = *(const bf16x8*)((const char*)h1s + (size_t)bid * 16384 + 8192 + tid * 16);

    // (2) preload B fragments from img2 (L2-hot) + bias
    const float bias = b2[n];
    bf16x8 bfr[8];
#pragma unroll
    for (int h = 0; h < 2; ++h)
#pragma unroll
        for (int kst = 0; kst < 4; ++kst)
            bfr[h * 4 + kst] = *(const bf16x8*)((const char*)img2 + h * 32768 + n * 256 + ((kst * 64 + lk * 16) ^ sx));

    // (3) BN1 coefficients from 8 replicas
    if (tid < 256) {
        float s = 0.f, q = 0.f;
#pragma unroll
        for (int r = 0; r < 8; ++r) { s += part1[r * 512 + tid]; q += part1[r * 512 + 256 + tid]; }
        float mu = s * INV_B;
        float var = fmaf(q, INV_B, -mu * mu);
        float rs = rsqrtf(var + BN_EPS_C);
        float a = g1[tid] * rs;
        a1s[tid] = a;
        c1s[tid] = fmaf(-mu, a, be1[tid]);
    }
    __syncthreads();

    // (4) transform + write A tile (value transform, layout preserved)
#pragma unroll
    for (int it = 0; it < 2; ++it) {
        int a = it * 8192 + tid * 16;
        int r = a >> 9, ks = a & 511;
        int k0 = (ks ^ ((r & 7) << 4)) >> 1;
        bf16x8 hv = it ? hv1 : hv0;
        bf16x8 sv;
#pragma unroll
        for (int j = 0; j < 8; ++j) {
            float f = bf2f((unsigned short)hv[j]);
            f = fmaf(a1s[k0 + j], f, c1s[k0 + j]);
            sv[j] = (short)f2bf(f);
        }
        *(bf16x8*)(As + a) = sv;
    }
    __syncthreads();

    f32x4 acc[2];
    acc[0] = (f32x4){0.f, 0.f, 0.f, 0.f};
    acc[1] = (f32x4){0.f, 0.f, 0.f, 0.f};
#pragma unroll
    for (int k8 = 0; k8 < 8; ++k8) {
        int kb = (k8 * 64 + lk * 16) ^ ((lr & 7) << 4);   // (16+lr)&7 == lr&7
        bf16x8 a0 = *(const bf16x8*)(As + lr * 512 + kb);
        bf16x8 a1v = *(const bf16x8*)(As + (16 + lr) * 512 + kb);
        acc[0] = __builtin_amdgcn_mfma_f32_16x16x32_bf16(a0, bfr[k8], acc[0], 0, 0, 0);
        acc[1] = __builtin_amdgcn_mfma_f32_16x16x32_bf16(a1v, bfr[k8], acc[1], 0, 0, 0);
    }

    // epilogue
    {
        float s = 0.f, q = 0.f;
#pragma unroll
        for (int mi = 0; mi < 2; ++mi)
#pragma unroll
            for (int reg = 0; reg < 4; ++reg) {
                int rl = mi * 16 + lk * 4 + reg;
                float v = fmaxf(acc[mi][reg] + bias, 0.f);
                unsigned short hb = f2bf(v);
                float vr = bf2f(hb);
                s += vr; q += vr * vr;
                *(unsigned short*)(Bnc + swz256(rl, n * 2)) = hb;
            }
        s += __shfl_xor(s, 16); s += __shfl_xor(s, 32);
        q += __shfl_xor(q, 16); q += __shfl_xor(q, 32);
        if (lk == 0) { sstat[n] = s; sstat[128 + n] = q; }
    }
    __syncthreads();

    // dump 8 KB tile + stats replica add
    *(bf16x8*)((char*)h2s + (size_t)bid * 8192 + tid * 16) = *(const bf16x8*)(Bnc + tid * 16);
    if (tid < 256) atomicAdd(&part2[(size_t)(bid & 7) * 256 + tid], sstat[tid]);
}

// ---------------------------------------------------------------------------
// K3: BN2 folded into W3; per-row dot on h2s image (swizzle-aware reads)
//     + precomputed wide + sigmoid. 512 blocks x 32 rows.
// ---------------------------------------------------------------------------
__global__ __launch_bounds__(128, 4) void wd_k3(
    const float* __restrict__ wideB, const float* __restrict__ wide_b,
    const unsigned short* __restrict__ h2s, const float* __restrict__ part2,
    const float* __restrict__ g2, const float* __restrict__ be2,
    const float* __restrict__ W3, const float* __restrict__ b3,
    float* __restrict__ out)
{
    __shared__ float af[128], cf[128];
    const int tid = threadIdx.x, bid = blockIdx.x;
    const int r = tid >> 2, kq = tid & 3;
    const int row = bid * 32 + r;

    float wide = 0.f;
    if (kq == 0) wide = wideB[row];

    {
        float s = 0.f, q = 0.f;
#pragma unroll
        for (int rr = 0; rr < 8; ++rr) { s += part2[rr * 256 + tid]; q += part2[rr * 256 + 128 + tid]; }
        float mu = s * INV_B;
        float var = fmaf(q, INV_B, -mu * mu);
        float rs = rsqrtf(var + BN_EPS_C);
        float a = g2[tid] * rs;
        float c = fmaf(-mu, a, be2[tid]);
        float w3 = W3[tid];
        af[tid] = a * w3;
        cf[tid] = c * w3;
    }
    __syncthreads();

    const char* tb = (const char*)h2s + (size_t)bid * 8192 + r * 256;
    float acc = 0.f;
#pragma unroll
    for (int j = 0; j < 4; ++j) {
        int ks = (kq * 64 + j * 16) ^ ((r & 7) << 4);
        bf16x8 hv = *(const bf16x8*)(tb + ks);
#pragma unroll
        for (int e = 0; e < 8; ++e) {
            float h = bf2f((unsigned short)hv[e]);
            int k = kq * 32 + j * 8 + e;
            acc += fmaf(h, af[k], cf[k]);
        }
    }
    acc += __shfl_xor(acc, 1);
    acc += __shfl_xor(acc, 2);
    if (kq == 0) {
        float logit = acc + b3[0] + wide_b[0] + wide;
        out[row] = 1.f / (1.f + expf(-logit));
    }
}

extern "C" void kernel_launch(void* const* d_in, const int* in_sizes, int n_in,
                              void* d_out, int out_size, void* d_ws, size_t ws_size,
                              hipStream_t stream)
{
    const int*   ui     = (const int*)d_in[0];
    const int*   ii     = (const int*)d_in[1];
    const float* wide_w = (const float*)d_in[2];
    const float* wide_b = (const float*)d_in[3];
    const float* utab   = (const float*)d_in[4];
    const float* itab   = (const float*)d_in[5];
    const float* W1     = (const float*)d_in[6];
    const float* b1     = (const float*)d_in[7];
    const float* g1     = (const float*)d_in[8];
    const float* be1    = (const float*)d_in[9];
    const float* W2     = (const float*)d_in[10];
    const float* b2     = (const float*)d_in[11];
    const float* g2     = (const float*)d_in[12];
    const float* be2    = (const float*)d_in[13];
    const float* W3     = (const float*)d_in[14];
    const float* b3     = (const float*)d_in[15];
    float* outp = (float*)d_out;

    char* base = (char*)d_ws;
    float* part1 = (float*)base;                                   // 8*512 f32 = 16 KB
    float* part2 = (float*)(base + 16384);                         // 8*256 f32 = 8 KB
    unsigned short* img1 = (unsigned short*)(base + 49152);        // 64 KB
    unsigned short* img2 = (unsigned short*)(base + 49152 + 65536);
    float* wideB = (float*)(base + 49152 + 131072);                // 64 KB
    unsigned short* h1s  = (unsigned short*)(base + 49152 + 131072 + 65536);      // 8 MB
    unsigned short* h2s  = (unsigned short*)(base + 49152 + 131072 + 65536 + (size_t)512 * 16384);

    wd_k0<<<48, 256, 0, stream>>>(W1, W2, img1, img2, part1);
    wd_k1<<<512, 512, 0, stream>>>(ui, ii, utab, itab, wide_w, img1, b1, h1s, wideB, part1);
    wd_k2<<<512, 512, 0, stream>>>(h1s, part1, g1, be1, img2, b2, h2s, part2);
    wd_k3<<<512, 128, 0, stream>>>(wideB, wide_b, h2s, part2, g2, be2, W3, b3, outp);
}